// Round 1
// baseline (402.002 us; speedup 1.0000x reference)
//
#include <hip/hip_runtime.h>
#include <stdint.h>

// T,B,I,H,K = 200,2048,128,128,4
#define T_DIM 200
#define B_DIM 2048
#define I_DIM 128
#define H_DIM 128
#define TS    32      // t rows per tile

typedef float  f32x4  __attribute__((ext_vector_type(4)));
typedef __bf16 bf16x8 __attribute__((ext_vector_type(8)));

union BF8 { ushort4 u2[2]; bf16x8 v; };

// native cast -> v_cvt_pk_bf16_f32 pairs (RNE), ~4x fewer VALU than manual RNE
static __device__ __forceinline__ unsigned short f2bf(float f) {
    union { __bf16 b; unsigned short u; } c; c.b = (__bf16)f;
    return c.u;
}
static __device__ __forceinline__ float bf2f(unsigned short s) {
    union { unsigned u; float f; } c; c.u = ((unsigned)s) << 16;
    return c.f;
}
static __device__ __forceinline__ ushort4 cvt4(float4 v) {
    return make_ushort4(f2bf(v.x), f2bf(v.y), f2bf(v.z), f2bf(v.w));
}

// One block per b; ~29 KB LDS. Changes vs prior version:
//  * phase A: 8-way t-parallel float4 column sums (serial chain 24 rounds -> ~4)
//  * T14 reg-staged tile prefetch: tile j+1 loads issued while tile j computes
//  * native bf16 casts (cvt_pk) in staging / x1 writes
//  * E phase folds h-group pairs with shfl_xor(32) before LDS partial write
__global__ __launch_bounds__(256, 4) void fused_kernel(
    const float* __restrict__ x, const int* __restrict__ lengths,
    const float* __restrict__ w0, const float* __restrict__ w1,
    const float* __restrict__ b1, const float* __restrict__ w2,
    const float* __restrict__ w3, float* __restrict__ out)
{
    __shared__ __align__(16) unsigned short xs[TS][136];   //  8704 B
    __shared__ __align__(16) unsigned short x1s[TS][130];  //  8320 B (65 dw stride: 2-way only)
    __shared__ __align__(16) float attp[TS][36];           //  4608 B (also psum / hacc2 reuse)
    __shared__ __align__(16) float attk[TS][4];            //   512 B
    __shared__ __align__(16) float ektL[H_DIM][4];         //  2048 B
    __shared__ __align__(16) float x2ls[4][H_DIM];         //  2048 B
    __shared__ __align__(16) float w0s[H_DIM];             //   512 B
    __shared__ __align__(16) unsigned short axl[4][136];   //  1088 B
    __shared__ __align__(16) unsigned short ams[4][136];   //  1088 B
    // total ~28.9 KB

    const int b    = blockIdx.x;
    const int tid  = threadIdx.x;
    const int lane = tid & 63;
    const int wv   = tid >> 6;
    const int l15  = lane & 15;
    const int quad = lane >> 4;
    const int L     = lengths[b];
    const int start = (L > 4) ? (L - 4) : 0;
    const int nv    = (L < 4) ? L : 4;

    if (tid < 128) w0s[tid] = w0[tid];

    // staging geometry: thread covers rows it*8+sr0, 16B column slot sf4
    const int sr0 = tid >> 5;   // 0..7
    const int sf4 = tid & 31;   // 0..31

    // ---- prefetch tile 0 into regs (in flight through phases A and B) ----
    float4 stg[4];
    #pragma unroll
    for (int it = 0; it < 4; ++it) {
        const int t = it * 8 + sr0;
        stg[it] = make_float4(0.f, 0.f, 0.f, 0.f);
        if (t < L)
            stg[it] = *(const float4*)(x + ((size_t)t * B_DIM + b) * I_DIM + sf4 * 4);
    }

    // ---- labeled-row loads issued early (consumed after psum reduce) ----
    const int i = tid & 127;
    const float* xp = x + (size_t)b * I_DIM + i;   // + t*B*I walks time
    float v0 = 0.f, v1 = 0.f, v2 = 0.f, v3 = 0.f;
    if (tid < 128) {
        v0 = xp[(size_t)(start + 0) * (B_DIM * I_DIM)];
        v1 = xp[(size_t)(start + 1) * (B_DIM * I_DIM)];
        v2 = xp[(size_t)(start + 2) * (B_DIM * I_DIM)];
        v3 = xp[(size_t)(start + 3) * (B_DIM * I_DIM)];
    }

    // ---- preload w1 B-frags + bias (regs; independent of everything) ----
    bf16x8 bfr[2][4];
    float  bias[2];
    #pragma unroll
    for (int nt = 0; nt < 2; ++nt) {
        const int n = wv * 32 + nt * 16 + l15;
        bias[nt] = b1[n];
        #pragma unroll
        for (int ks = 0; ks < 4; ++ks) {
            const int kc = ks * 32 + quad * 8;
            const float4 p0 = *(const float4*)(w1 + (size_t)n * I_DIM + kc);
            const float4 p1 = *(const float4*)(w1 + (size_t)n * I_DIM + kc + 4);
            BF8 t;
            t.u2[0] = cvt4(p0);
            t.u2[1] = cvt4(p1);
            bfr[nt][ks] = t.v;
        }
    }

    // ---- A: 8-way t-parallel column sums over t in [0,start) ----
    {
        const float* xq = x + (size_t)b * I_DIM + sf4 * 4;
        const size_t RS = (size_t)B_DIM * I_DIM;
        f32x4 s0 = (f32x4){0.f, 0.f, 0.f, 0.f};
        f32x4 s1 = s0, s2 = s0, s3 = s0;
        int t = sr0;
        for (; t + 24 < start; t += 32) {       // 4 independent f32x4 loads in flight
            s0 += *(const f32x4*)(xq + (size_t)(t     ) * RS);
            s1 += *(const f32x4*)(xq + (size_t)(t +  8) * RS);
            s2 += *(const f32x4*)(xq + (size_t)(t + 16) * RS);
            s3 += *(const f32x4*)(xq + (size_t)(t + 24) * RS);
        }
        for (; t < start; t += 8)
            s0 += *(const f32x4*)(xq + (size_t)t * RS);
        const f32x4 s = (s0 + s1) + (s2 + s3);
        float* psum = &attp[0][0];              // reused as [8][132] partials (1056 fl)
        *(f32x4*)&psum[sr0 * 132 + sf4 * 4] = s;
    }
    __syncthreads();

    if (tid < 128) {
        const float* psum = &attp[0][0];
        float p = 0.f;
        #pragma unroll
        for (int g = 0; g < 8; ++g) p += psum[g * 132 + i];
        // labeled rows t = start..start+3 (always < T; k>=nv garbage is masked later)
        const float p0 = p + v0, p1 = p0 + v1, p2 = p1 + v2, p3 = p2 + v3;
        axl[0][i] = f2bf(v0); axl[1][i] = f2bf(v1);
        axl[2][i] = f2bf(v2); axl[3][i] = f2bf(v3);
        ams[0][i] = f2bf(p0 / (float)(start + 1));
        ams[1][i] = f2bf(p1 / (float)(start + 2));
        ams[2][i] = f2bf(p2 / (float)(start + 3));
        ams[3][i] = f2bf(p3 / (float)(start + 4));
    }
    __syncthreads();

    // ---- B: mini-GEMM {x_lab, m_s}@{w2,w3}^T -> ektL=exp(-c), x2ls ----
    #pragma unroll
    for (int nt = 0; nt < 2; ++nt) {
        const int n = wv * 32 + nt * 16 + l15;
        f32x4 c1 = (f32x4){0.f, 0.f, 0.f, 0.f};
        f32x4 c2 = (f32x4){0.f, 0.f, 0.f, 0.f};
        #pragma unroll
        for (int ks = 0; ks < 4; ++ks) {
            const int kc = ks * 32 + quad * 8;
            const bf16x8 a1 = *(const bf16x8*)&axl[l15 & 3][kc];
            const bf16x8 a2 = *(const bf16x8*)&ams[l15 & 3][kc];
            const float4 q0 = *(const float4*)(w2 + (size_t)n * I_DIM + kc);
            const float4 q1 = *(const float4*)(w2 + (size_t)n * I_DIM + kc + 4);
            const float4 r0 = *(const float4*)(w3 + (size_t)n * I_DIM + kc);
            const float4 r1 = *(const float4*)(w3 + (size_t)n * I_DIM + kc + 4);
            BF8 bw2, bw3;
            bw2.u2[0] = cvt4(q0); bw2.u2[1] = cvt4(q1);
            bw3.u2[0] = cvt4(r0); bw3.u2[1] = cvt4(r1);
            c1 = __builtin_amdgcn_mfma_f32_16x16x32_bf16(a1, bw2.v, c1, 0, 0, 0);
            c2 = __builtin_amdgcn_mfma_f32_16x16x32_bf16(a2, bw3.v, c2, 0, 0, 0);
        }
        if (quad == 0) {    // D rows 0..3 = labeled k
            #pragma unroll
            for (int r = 0; r < 4; ++r) {
                x2ls[r][n] = c1[r];
                ektL[n][r] = __builtin_amdgcn_exp2f(-1.44269504f * (c1[r] + c2[r]));
            }
        }
    }
    __syncthreads();

    // ---- C: tile loop ----
    const int sq = tid & 31;          // E-phase s within tile
    const int hg = tid >> 5;          // E-phase h-group (8 groups x 16 h)
    const int hcol = tid & 127;       // ACC h
    const int half = tid >> 7;
    float hacc0 = 0.f, hacc1 = 0.f, hacc2v = 0.f, hacc3 = 0.f;

    for (int t0 = 0; t0 < L; t0 += TS) {
        // commit staged tile regs -> LDS (rows >= L are zeros: downstream finite)
        #pragma unroll
        for (int it = 0; it < 4; ++it)
            *(ushort4*)&xs[it * 8 + sr0][sf4 * 4] = cvt4(stg[it]);
        __syncthreads();

        // issue next tile's loads NOW; latency hides under MFMA+E+ACC
        {
            const int tn = t0 + TS;
            #pragma unroll
            for (int it = 0; it < 4; ++it) {
                const int t = tn + it * 8 + sr0;
                stg[it] = make_float4(0.f, 0.f, 0.f, 0.f);
                if (t < L)
                    stg[it] = *(const float4*)(
                        x + ((size_t)t * B_DIM + b) * I_DIM + sf4 * 4);
            }
        }

        // MFMA: x1 tile (32 t x 128 h), write [t][h] bf16
        #pragma unroll
        for (int mt = 0; mt < 2; ++mt) {
            bf16x8 afr[4];
            #pragma unroll
            for (int ks = 0; ks < 4; ++ks)
                afr[ks] = *(const bf16x8*)&xs[mt * 16 + l15][ks * 32 + quad * 8];
            #pragma unroll
            for (int nt = 0; nt < 2; ++nt) {
                f32x4 acc = (f32x4){0.f, 0.f, 0.f, 0.f};
                #pragma unroll
                for (int ks = 0; ks < 4; ++ks)
                    acc = __builtin_amdgcn_mfma_f32_16x16x32_bf16(
                        afr[ks], bfr[nt][ks], acc, 0, 0, 0);
                const int h = wv * 32 + nt * 16 + l15;
                const int tr = mt * 16 + quad * 4;
                #pragma unroll
                for (int r = 0; r < 4; ++r)
                    x1s[tr + r][h] = f2bf(acc[r] + bias[nt]);
            }
        }
        __syncthreads();

        // E: att partials; thread (sq, hg) covers 16 h; one exp + 4 rcp per h.
        // shfl_xor(32) folds the wave's two h-groups -> half the attp traffic.
        {
            const int h0 = hg * 16;
            f32x4 a = (f32x4){0.f, 0.f, 0.f, 0.f};
            #pragma unroll
            for (int hh = 0; hh < 16; hh += 2) {
                const int h = h0 + hh;
                const unsigned xv2 = *(const unsigned*)&x1s[sq][h];
                const float xa = bf2f((unsigned short)(xv2 & 0xFFFFu));
                const float xb = bf2f((unsigned short)(xv2 >> 16));
                const float Ea = __builtin_amdgcn_exp2f(-1.44269504f * xa);
                const float Eb = __builtin_amdgcn_exp2f(-1.44269504f * xb);
                const f32x4 eka = *(const f32x4*)&ektL[h][0];
                const f32x4 ekb = *(const f32x4*)&ektL[h + 1][0];
                const float wa = w0s[h], wb = w0s[h + 1];
                #pragma unroll
                for (int k = 0; k < 4; ++k)
                    a[k] += wa * __builtin_amdgcn_rcpf(1.f + Ea * eka[k])
                          + wb * __builtin_amdgcn_rcpf(1.f + Eb * ekb[k]);
            }
            #pragma unroll
            for (int k = 0; k < 4; ++k)
                a[k] += __shfl_xor(a[k], 32);
            if (!(tid & 32))
                *(f32x4*)&attp[sq][(tid >> 6) * 4] = a;   // 4 wave-partials
        }
        __syncthreads();

        // reduce 4 wave partials + mask (NaN/garbage-safe: select after sum)
        if (tid < TS) {
            const int s = t0 + tid;
            f32x4 sm = (f32x4){0.f, 0.f, 0.f, 0.f};
            #pragma unroll
            for (int g = 0; g < 4; ++g)
                sm += *(const f32x4*)&attp[tid][g * 4];
            f32x4 o;
            o[0] = (0 < nv && s <= start    ) ? sm[0] : 0.f;
            o[1] = (1 < nv && s <= start + 1) ? sm[1] : 0.f;
            o[2] = (2 < nv && s <= start + 2) ? sm[2] : 0.f;
            o[3] = (3 < nv && s <= start + 3) ? sm[3] : 0.f;
            *(f32x4*)&attk[tid][0] = o;
        }
        __syncthreads();

        // ACC: hacc[k][h] += sum_s att[k][s]*x1[s][h]; halves split the 16+16 rows
        {
            const int sbase = half * 16;
            #pragma unroll
            for (int s2 = 0; s2 < 16; ++s2) {
                const int srow = sbase + s2;
                const f32x4 a4 = *(const f32x4*)&attk[srow][0];   // broadcast
                const float xv = bf2f(x1s[srow][hcol]);           // row-broadcast, 2-way
                hacc0 += a4[0] * xv; hacc1 += a4[1] * xv;
                hacc2v += a4[2] * xv; hacc3 += a4[3] * xv;
            }
        }
        __syncthreads();
    }

    // ---- epilogue: combine halves via LDS (attp reuse), +x2_lab, mask, store ----
    {
        float* h2 = &attp[0][0];    // [128][4]
        if (half == 1) {
            *(f32x4*)&h2[hcol * 4] = (f32x4){hacc0, hacc1, hacc2v, hacc3};
        }
        __syncthreads();
        if (tid < 128) {
            const f32x4 o = *(const f32x4*)&h2[hcol * 4];
            hacc0 += o[0]; hacc1 += o[1]; hacc2v += o[2]; hacc3 += o[3];
            out[((size_t)b * 4 + 0) * H_DIM + hcol] = (0 < nv) ? hacc0 + x2ls[0][hcol] : 0.f;
            out[((size_t)b * 4 + 1) * H_DIM + hcol] = (1 < nv) ? hacc1 + x2ls[1][hcol] : 0.f;
            out[((size_t)b * 4 + 2) * H_DIM + hcol] = (2 < nv) ? hacc2v + x2ls[2][hcol] : 0.f;
            out[((size_t)b * 4 + 3) * H_DIM + hcol] = (3 < nv) ? hacc3 + x2ls[3][hcol] : 0.f;
        }
    }
}

extern "C" void kernel_launch(void* const* d_in, const int* in_sizes, int n_in,
                              void* d_out, int out_size, void* d_ws, size_t ws_size,
                              hipStream_t stream) {
    (void)in_sizes; (void)n_in; (void)out_size; (void)d_ws; (void)ws_size;
    const float* x       = (const float*)d_in[0];
    const int*   lengths = (const int*)d_in[1];
    // d_in[2] = label_len (==4, hard-coded)
    const float* w0 = (const float*)d_in[3];
    const float* w1 = (const float*)d_in[4];
    const float* b1 = (const float*)d_in[5];
    const float* w2 = (const float*)d_in[6];
    const float* w3 = (const float*)d_in[7];
    float* out = (float*)d_out;

    fused_kernel<<<dim3(B_DIM), 256, 0, stream>>>(x, lengths, w0, w1, b1, w2, w3, out);
}

// Round 3
// 369.680 us; speedup vs baseline: 1.0874x; 1.0874x over previous
//
#include <hip/hip_runtime.h>
#include <stdint.h>

// T,B,I,H,K = 200,2048,128,128,4
#define T_DIM 200
#define B_DIM 2048
#define I_DIM 128
#define H_DIM 128
#define TS    32      // t rows per tile

typedef float  f32x4  __attribute__((ext_vector_type(4)));
typedef __bf16 bf16x8 __attribute__((ext_vector_type(8)));

union BF8 { ushort4 u2[2]; bf16x8 v; };

// native cast -> v_cvt_pk_bf16_f32 (RNE)
static __device__ __forceinline__ unsigned short f2bf(float f) {
    union { __bf16 b; unsigned short u; } c; c.b = (__bf16)f; return c.u;
}
static __device__ __forceinline__ float bf2f(unsigned short s) {
    union { unsigned u; float f; } c; c.u = ((unsigned)s) << 16;
    return c.f;
}
static __device__ __forceinline__ ushort4 cvt4(float4 v) {
    return make_ushort4(f2bf(v.x), f2bf(v.y), f2bf(v.z), f2bf(v.w));
}

// One block per b; ~29 KB LDS -> 5 blocks/CU. Known-good structure (round 0/1):
// phases A (8-way t-parallel column prefix sums), B (mini-GEMM -> ekt/x2ls),
// C (tile loop: stage -> MFMA x1 -> E att partials + shfl fold -> masked
// reduce -> ACC). NO register prefetch across barriers (round-1 spill lesson:
// holding 16 VGPRs across the tile loop spilled ~78 MB of scratch traffic).
__global__ __launch_bounds__(256, 4) void fused_kernel(
    const float* __restrict__ x, const int* __restrict__ lengths,
    const float* __restrict__ w0, const float* __restrict__ w1,
    const float* __restrict__ b1, const float* __restrict__ w2,
    const float* __restrict__ w3, float* __restrict__ out)
{
    __shared__ __align__(16) unsigned short xs[TS][136];   //  8704 B
    __shared__ __align__(16) unsigned short x1s[TS][130];  //  8320 B (65 dw stride: 2-way only)
    __shared__ __align__(16) float attp[TS][36];           //  4608 B (also psum / hacc2 reuse)
    __shared__ __align__(16) float attk[TS][4];            //   512 B
    __shared__ __align__(16) float ektL[H_DIM][4];         //  2048 B
    __shared__ __align__(16) float x2ls[4][H_DIM];         //  2048 B
    __shared__ __align__(16) float w0s[H_DIM];             //   512 B
    __shared__ __align__(16) unsigned short axl[4][136];   //  1088 B
    __shared__ __align__(16) unsigned short ams[4][136];   //  1088 B
    // total ~28.9 KB

    const int b    = blockIdx.x;
    const int tid  = threadIdx.x;
    const int lane = tid & 63;
    const int wv   = tid >> 6;
    const int l15  = lane & 15;
    const int quad = lane >> 4;
    const int L     = lengths[b];
    const int start = (L > 4) ? (L - 4) : 0;
    const int nv    = (L < 4) ? L : 4;

    if (tid < 128) w0s[tid] = w0[tid];

    // ---- labeled-row loads issued early (consumed after psum reduce) ----
    const int i = tid & 127;
    const float* xp = x + (size_t)b * I_DIM + i;   // + t*B*I walks time
    float v0 = 0.f, v1 = 0.f, v2 = 0.f, v3 = 0.f;
    if (tid < 128) {
        v0 = xp[(size_t)(start + 0) * (B_DIM * I_DIM)];
        v1 = xp[(size_t)(start + 1) * (B_DIM * I_DIM)];
        v2 = xp[(size_t)(start + 2) * (B_DIM * I_DIM)];
        v3 = xp[(size_t)(start + 3) * (B_DIM * I_DIM)];
    }

    // ---- preload w1 B-frags + bias (regs; independent of everything) ----
    bf16x8 bfr[2][4];
    float  bias[2];
    #pragma unroll
    for (int nt = 0; nt < 2; ++nt) {
        const int n = wv * 32 + nt * 16 + l15;
        bias[nt] = b1[n];
        #pragma unroll
        for (int ks = 0; ks < 4; ++ks) {
            const int kc = ks * 32 + quad * 8;
            const float4 p0 = *(const float4*)(w1 + (size_t)n * I_DIM + kc);
            const float4 p1 = *(const float4*)(w1 + (size_t)n * I_DIM + kc + 4);
            BF8 t;
            t.u2[0] = cvt4(p0);
            t.u2[1] = cvt4(p1);
            bfr[nt][ks] = t.v;
        }
    }

    // ---- A: 8-way t-parallel column sums over t in [0,start) ----
    const int sr0 = tid >> 5;   // 0..7
    const int sf4 = tid & 31;   // 0..31
    {
        const float* xq = x + (size_t)b * I_DIM + sf4 * 4;
        const size_t RS = (size_t)B_DIM * I_DIM;
        f32x4 s0 = (f32x4){0.f, 0.f, 0.f, 0.f};
        f32x4 s1 = s0, s2 = s0, s3 = s0;
        int t = sr0;
        for (; t + 24 < start; t += 32) {       // 4 independent f32x4 loads in flight
            s0 += *(const f32x4*)(xq + (size_t)(t     ) * RS);
            s1 += *(const f32x4*)(xq + (size_t)(t +  8) * RS);
            s2 += *(const f32x4*)(xq + (size_t)(t + 16) * RS);
            s3 += *(const f32x4*)(xq + (size_t)(t + 24) * RS);
        }
        for (; t < start; t += 8)
            s0 += *(const f32x4*)(xq + (size_t)t * RS);
        const f32x4 s = (s0 + s1) + (s2 + s3);
        float* psum = &attp[0][0];              // attp reused as [8][132] partials
        *(f32x4*)&psum[sr0 * 132 + sf4 * 4] = s;
    }
    __syncthreads();

    if (tid < 128) {
        const float* psum = &attp[0][0];
        float p = 0.f;
        #pragma unroll
        for (int g = 0; g < 8; ++g) p += psum[g * 132 + i];
        // labeled rows t = start..start+3 (always < T; k>=nv garbage masked later)
        const float p0 = p + v0, p1 = p0 + v1, p2 = p1 + v2, p3 = p2 + v3;
        axl[0][i] = f2bf(v0); axl[1][i] = f2bf(v1);
        axl[2][i] = f2bf(v2); axl[3][i] = f2bf(v3);
        ams[0][i] = f2bf(p0 / (float)(start + 1));
        ams[1][i] = f2bf(p1 / (float)(start + 2));
        ams[2][i] = f2bf(p2 / (float)(start + 3));
        ams[3][i] = f2bf(p3 / (float)(start + 4));
    }
    __syncthreads();

    // ---- B: mini-GEMM {x_lab, m_s}@{w2,w3}^T -> ektL=exp(-c), x2ls ----
    #pragma unroll
    for (int nt = 0; nt < 2; ++nt) {
        const int n = wv * 32 + nt * 16 + l15;
        f32x4 c1 = (f32x4){0.f, 0.f, 0.f, 0.f};
        f32x4 c2 = (f32x4){0.f, 0.f, 0.f, 0.f};
        #pragma unroll
        for (int ks = 0; ks < 4; ++ks) {
            const int kc = ks * 32 + quad * 8;
            const bf16x8 a1 = *(const bf16x8*)&axl[l15 & 3][kc];
            const bf16x8 a2 = *(const bf16x8*)&ams[l15 & 3][kc];
            const float4 q0 = *(const float4*)(w2 + (size_t)n * I_DIM + kc);
            const float4 q1 = *(const float4*)(w2 + (size_t)n * I_DIM + kc + 4);
            const float4 r0 = *(const float4*)(w3 + (size_t)n * I_DIM + kc);
            const float4 r1 = *(const float4*)(w3 + (size_t)n * I_DIM + kc + 4);
            BF8 bw2, bw3;
            bw2.u2[0] = cvt4(q0); bw2.u2[1] = cvt4(q1);
            bw3.u2[0] = cvt4(r0); bw3.u2[1] = cvt4(r1);
            c1 = __builtin_amdgcn_mfma_f32_16x16x32_bf16(a1, bw2.v, c1, 0, 0, 0);
            c2 = __builtin_amdgcn_mfma_f32_16x16x32_bf16(a2, bw3.v, c2, 0, 0, 0);
        }
        if (quad == 0) {    // D rows 0..3 = labeled k
            #pragma unroll
            for (int r = 0; r < 4; ++r) {
                x2ls[r][n] = c1[r];
                ektL[n][r] = __builtin_amdgcn_exp2f(-1.44269504f * (c1[r] + c2[r]));
            }
        }
    }
    __syncthreads();

    // ---- C: tile loop ----
    const int sq = tid & 31;          // E-phase s within tile
    const int hg = tid >> 5;          // E-phase h-group (8 groups x 16 h)
    const int hcol = tid & 127;       // ACC h
    const int half = tid >> 7;
    float hacc0 = 0.f, hacc1 = 0.f, hacc2v = 0.f, hacc3 = 0.f;

    for (int t0 = 0; t0 < L; t0 += TS) {
        const int nrows = (L - t0 < TS) ? (L - t0) : TS;

        // stage (zero-fill invalid rows -> everything downstream finite);
        // loads consumed immediately, nothing held across barriers (no spill)
        #pragma unroll
        for (int it = 0; it < 4; ++it) {
            const int sl = tid + it * 256;          // TS*32 = 1024 slots
            const int r = sl >> 5, f4 = sl & 31;
            ushort4 w = make_ushort4(0, 0, 0, 0);
            if (r < nrows) {
                const float4 v = *(const float4*)(
                    x + ((size_t)(t0 + r) * B_DIM + b) * I_DIM + f4 * 4);
                w = cvt4(v);
            }
            *(ushort4*)&xs[r][f4 * 4] = w;
        }
        __syncthreads();

        // MFMA: x1 tile (32 t x 128 h), write [t][h] bf16
        #pragma unroll
        for (int mt = 0; mt < 2; ++mt) {
            bf16x8 afr[4];
            #pragma unroll
            for (int ks = 0; ks < 4; ++ks)
                afr[ks] = *(const bf16x8*)&xs[mt * 16 + l15][ks * 32 + quad * 8];
            #pragma unroll
            for (int nt = 0; nt < 2; ++nt) {
                f32x4 acc = (f32x4){0.f, 0.f, 0.f, 0.f};
                #pragma unroll
                for (int ks = 0; ks < 4; ++ks)
                    acc = __builtin_amdgcn_mfma_f32_16x16x32_bf16(
                        afr[ks], bfr[nt][ks], acc, 0, 0, 0);
                const int h = wv * 32 + nt * 16 + l15;
                const int tr = mt * 16 + quad * 4;
                #pragma unroll
                for (int r = 0; r < 4; ++r)
                    x1s[tr + r][h] = f2bf(acc[r] + bias[nt]);
            }
        }
        __syncthreads();

        // E: att partials; thread (sq, hg) covers 16 h; one exp + 4 rcp per h.
        // shfl_xor(32) folds the wave's two h-groups -> half the attp traffic.
        {
            const int h0 = hg * 16;
            f32x4 a = (f32x4){0.f, 0.f, 0.f, 0.f};
            #pragma unroll
            for (int hh = 0; hh < 16; hh += 2) {
                const int h = h0 + hh;
                const unsigned xv2 = *(const unsigned*)&x1s[sq][h];
                const float xa = bf2f((unsigned short)(xv2 & 0xFFFFu));
                const float xb = bf2f((unsigned short)(xv2 >> 16));
                const float Ea = __builtin_amdgcn_exp2f(-1.44269504f * xa);
                const float Eb = __builtin_amdgcn_exp2f(-1.44269504f * xb);
                const f32x4 eka = *(const f32x4*)&ektL[h][0];
                const f32x4 ekb = *(const f32x4*)&ektL[h + 1][0];
                const float wa = w0s[h], wb = w0s[h + 1];
                #pragma unroll
                for (int k = 0; k < 4; ++k)
                    a[k] += wa * __builtin_amdgcn_rcpf(1.f + Ea * eka[k])
                          + wb * __builtin_amdgcn_rcpf(1.f + Eb * ekb[k]);
            }
            #pragma unroll
            for (int k = 0; k < 4; ++k)
                a[k] += __shfl_xor(a[k], 32);
            if (!(tid & 32))
                *(f32x4*)&attp[sq][(tid >> 6) * 4] = a;   // 4 wave-partials
        }
        __syncthreads();

        // reduce 4 wave partials + mask (NaN/garbage-safe: select after sum)
        if (tid < TS) {
            const int s = t0 + tid;
            f32x4 sm = (f32x4){0.f, 0.f, 0.f, 0.f};
            #pragma unroll
            for (int g = 0; g < 4; ++g)
                sm += *(const f32x4*)&attp[tid][g * 4];
            f32x4 o;
            o[0] = (0 < nv && s <= start    ) ? sm[0] : 0.f;
            o[1] = (1 < nv && s <= start + 1) ? sm[1] : 0.f;
            o[2] = (2 < nv && s <= start + 2) ? sm[2] : 0.f;
            o[3] = (3 < nv && s <= start + 3) ? sm[3] : 0.f;
            *(f32x4*)&attk[tid][0] = o;
        }
        __syncthreads();

        // ACC: hacc[k][h] += sum_s att[k][s]*x1[s][h]; halves split the 16+16 rows
        {
            const int sbase = half * 16;
            #pragma unroll
            for (int s2 = 0; s2 < 16; ++s2) {
                const int srow = sbase + s2;
                const f32x4 a4 = *(const f32x4*)&attk[srow][0];   // broadcast
                const float xv = bf2f(x1s[srow][hcol]);           // row-broadcast, 2-way
                hacc0 += a4[0] * xv; hacc1 += a4[1] * xv;
                hacc2v += a4[2] * xv; hacc3 += a4[3] * xv;
            }
        }
        __syncthreads();
    }

    // ---- epilogue: combine halves via LDS (attp reuse), +x2_lab, mask, store ----
    {
        float* h2 = &attp[0][0];    // [128][4]
        if (half == 1) {
            *(f32x4*)&h2[hcol * 4] = (f32x4){hacc0, hacc1, hacc2v, hacc3};
        }
        __syncthreads();
        if (tid < 128) {
            const f32x4 o = *(const f32x4*)&h2[hcol * 4];
            hacc0 += o[0]; hacc1 += o[1]; hacc2v += o[2]; hacc3 += o[3];
            out[((size_t)b * 4 + 0) * H_DIM + hcol] = (0 < nv) ? hacc0 + x2ls[0][hcol] : 0.f;
            out[((size_t)b * 4 + 1) * H_DIM + hcol] = (1 < nv) ? hacc1 + x2ls[1][hcol] : 0.f;
            out[((size_t)b * 4 + 2) * H_DIM + hcol] = (2 < nv) ? hacc2v + x2ls[2][hcol] : 0.f;
            out[((size_t)b * 4 + 3) * H_DIM + hcol] = (3 < nv) ? hacc3 + x2ls[3][hcol] : 0.f;
        }
    }
}

extern "C" void kernel_launch(void* const* d_in, const int* in_sizes, int n_in,
                              void* d_out, int out_size, void* d_ws, size_t ws_size,
                              hipStream_t stream) {
    (void)in_sizes; (void)n_in; (void)out_size; (void)d_ws; (void)ws_size;
    const float* x       = (const float*)d_in[0];
    const int*   lengths = (const int*)d_in[1];
    // d_in[2] = label_len (==4, hard-coded)
    const float* w0 = (const float*)d_in[3];
    const float* w1 = (const float*)d_in[4];
    const float* b1 = (const float*)d_in[5];
    const float* w2 = (const float*)d_in[6];
    const float* w3 = (const float*)d_in[7];
    float* out = (float*)d_out;

    fused_kernel<<<dim3(B_DIM), 256, 0, stream>>>(x, lengths, w0, w1, b1, w2, w3, out);
}